// Round 1
// baseline (675.705 us; speedup 1.0000x reference)
//
#include <hip/hip_runtime.h>
#include <hip/hip_bf16.h>

// Problem shape (fixed by reference): x (2,4096,2048) f32, W (8192,2048) f32,
// bias (8192,) f32, out (2,4096,8192) f32.  GEMM: M=8192, N=8192, K=2048.
#define M_DIM 8192
#define N_DIM 8192
#define K_DIM 2048
#define BM 128
#define BN 128
#define BK 32

typedef __attribute__((ext_vector_type(8))) short bf16x8;   // 8 bf16 in 4 VGPRs
typedef __attribute__((ext_vector_type(4))) float floatx4;  // MFMA C/D

__device__ inline void gload_lds16(const void* g, void* l) {
  // global -> LDS direct DMA, 16 B per lane; LDS dest is wave-uniform base + lane*16
  __builtin_amdgcn_global_load_lds(
      (const __attribute__((address_space(1))) unsigned int*)g,
      (__attribute__((address_space(3))) unsigned int*)l, 16, 0, 0);
}

__device__ inline short f2bf(float f) {
  __hip_bfloat16 h = __float2bfloat16(f);  // RNE
  return *(short*)&h;
}

__device__ inline float round_bf16(float f) {
  __hip_bfloat16 h = __float2bfloat16(f);
  return __bfloat162float(h);
}

// ---------------- amax reduction: max(|src|) over n floats -> atomicMax bits ---
__global__ __launch_bounds__(256) void amax_kernel(const float* __restrict__ src,
                                                   int n,
                                                   unsigned int* __restrict__ out_bits) {
  int tid = threadIdx.x;
  int start = (blockIdx.x * 256 + tid) * 4;
  int stride = gridDim.x * 256 * 4;
  float m = 0.0f;
  for (int i = start; i < n; i += stride) {
    float4 v = *(const float4*)(src + i);
    m = fmaxf(m, fmaxf(fmaxf(fabsf(v.x), fabsf(v.y)), fmaxf(fabsf(v.z), fabsf(v.w))));
  }
  // wave-64 shuffle reduce
  for (int off = 32; off > 0; off >>= 1) m = fmaxf(m, __shfl_down(m, off));
  __shared__ float red[4];
  if ((tid & 63) == 0) red[tid >> 6] = m;
  __syncthreads();
  if (tid == 0) {
    m = fmaxf(fmaxf(red[0], red[1]), fmaxf(red[2], red[3]));
    atomicMax(out_bits, __float_as_uint(m));  // |x| >= 0: bit order == float order
  }
}

// ---------------- quantize: dst = bf16(src / (amax/448)) --------------------
__global__ __launch_bounds__(256) void quant_kernel(const float* __restrict__ src,
                                                    short* __restrict__ dst,
                                                    const unsigned int* __restrict__ amax_bits) {
  float scale = __uint_as_float(*amax_bits) / 448.0f;  // fp32 division, matches ref
  int idx = (blockIdx.x * 256 + threadIdx.x) * 8;
  float4 v0 = *(const float4*)(src + idx);
  float4 v1 = *(const float4*)(src + idx + 4);
  bf16x8 o;
  o[0] = f2bf(v0.x / scale);
  o[1] = f2bf(v0.y / scale);
  o[2] = f2bf(v0.z / scale);
  o[3] = f2bf(v0.w / scale);
  o[4] = f2bf(v1.x / scale);
  o[5] = f2bf(v1.y / scale);
  o[6] = f2bf(v1.z / scale);
  o[7] = f2bf(v1.w / scale);
  *(bf16x8*)(dst + idx) = o;
}

// ---------------- GEMM: C[m,n] = (sum_k A[m,k]*B[n,k]) rounded-bf16 * s + bias[n]
// m97 structure: 128x128 block, BK=32, 4 waves (2x2), each wave 4x4 tiles of
// 16x16x32 bf16 MFMA, staging via global_load_lds width=16, single LDS buffer.
__global__ __launch_bounds__(256, 2) void gemm_kernel(
    const short* __restrict__ A,   // Xq [M,K] bf16 bits
    const short* __restrict__ B,   // Wq [N,K] bf16 bits
    const float* __restrict__ bias,
    const unsigned int* __restrict__ amax_bits,  // [0]=x amax, [1]=w amax
    float* __restrict__ C) {
  __shared__ short As[BM * BK];  // [m][k], contiguous — matches load_lds lane order
  __shared__ short Bs[BN * BK];  // [n][k]

  const int tid = threadIdx.x;
  const int lane = tid & 63;
  const int waveId = tid >> 6;
  const int waveM = waveId >> 1;  // 0..1
  const int waveN = waveId & 1;   // 0..1
  const int m0 = blockIdx.y * BM;
  const int n0 = blockIdx.x * BN;

  // Staging: tile = 128 rows x 32 bf16 = 512 chunks of 16 B; 4 chunks per row.
  // Thread t handles chunks t and t+256 -> per wave each issue is lds base+lane*16.
  const int r0 = tid >> 2;      // row of chunk tid
  const int q0 = tid & 3;       // 16B chunk within row
  const short* aSrc0 = A + (long)(m0 + r0) * K_DIM + q0 * 8;
  const short* aSrc1 = A + (long)(m0 + r0 + 64) * K_DIM + q0 * 8;
  const short* bSrc0 = B + (long)(n0 + r0) * K_DIM + q0 * 8;
  const short* bSrc1 = B + (long)(n0 + r0 + 64) * K_DIM + q0 * 8;
  short* aDst0 = As + tid * 8;
  short* aDst1 = As + (tid + 256) * 8;
  short* bDst0 = Bs + tid * 8;
  short* bDst1 = Bs + (tid + 256) * 8;

  floatx4 acc[4][4] = {};

  const int am = waveM * 64 + (lane & 15);  // A row base (add i*16)
  const int bn = waveN * 64 + (lane & 15);  // B row base (add j*16)
  const int ak = (lane >> 4) * 8;           // k offset within BK

  for (int kt = 0; kt < K_DIM / BK; ++kt) {
    const int ko = kt * BK;
    gload_lds16(aSrc0 + ko, aDst0);
    gload_lds16(aSrc1 + ko, aDst1);
    gload_lds16(bSrc0 + ko, bDst0);
    gload_lds16(bSrc1 + ko, bDst1);
    __syncthreads();  // compiler drains vmcnt before barrier

    bf16x8 af[4], bfr[4];
#pragma unroll
    for (int i = 0; i < 4; ++i)
      af[i] = *(const bf16x8*)(As + (am + i * 16) * BK + ak);
#pragma unroll
    for (int j = 0; j < 4; ++j)
      bfr[j] = *(const bf16x8*)(Bs + (bn + j * 16) * BK + ak);

#pragma unroll
    for (int i = 0; i < 4; ++i)
#pragma unroll
      for (int j = 0; j < 4; ++j)
        acc[i][j] = __builtin_amdgcn_mfma_f32_16x16x32_bf16(af[i], bfr[j], acc[i][j], 0, 0, 0);

    __syncthreads();  // protect LDS before next stage
  }

  // Epilogue: ref = bf16(einsum).astype(f32) * (w_scale*x_scale) + bias
  const float sx = __uint_as_float(amax_bits[0]) / 448.0f;
  const float sw = __uint_as_float(amax_bits[1]) / 448.0f;
  const float s = sx * sw;
  const int col = lane & 15;
  const int rq = (lane >> 4) * 4;  // C/D: row = (lane>>4)*4 + reg, col = lane&15
#pragma unroll
  for (int j = 0; j < 4; ++j) {
    const int n = n0 + waveN * 64 + j * 16 + col;
    const float bv = bias[n];
#pragma unroll
    for (int i = 0; i < 4; ++i) {
      const int mBase = m0 + waveM * 64 + i * 16 + rq;
#pragma unroll
      for (int r = 0; r < 4; ++r) {
        float v = round_bf16(acc[i][j][r]);  // match XLA bf16 dot output demote
        C[(long)(mBase + r) * N_DIM + n] = v * s + bv;
      }
    }
  }
}

extern "C" void kernel_launch(void* const* d_in, const int* in_sizes, int n_in,
                              void* d_out, int out_size, void* d_ws, size_t ws_size,
                              hipStream_t stream) {
  const float* x = (const float*)d_in[0];     // (2,4096,2048)
  const float* w = (const float*)d_in[1];     // (8192,2048)
  const float* bias = (const float*)d_in[2];  // (8192,)
  float* out = (float*)d_out;

  // Workspace layout: [0..63] amax bits (u32[0]=x, u32[1]=w); then Xq; then Wq.
  unsigned int* bits = (unsigned int*)d_ws;
  short* xq = (short*)((char*)d_ws + 256);
  short* wq = (short*)((char*)d_ws + 256 + (size_t)M_DIM * K_DIM * sizeof(short));

  hipMemsetAsync(d_ws, 0, 64, stream);  // zero amax slots (ws is poisoned 0xAA)

  amax_kernel<<<1024, 256, 0, stream>>>(x, M_DIM * K_DIM, bits + 0);
  amax_kernel<<<1024, 256, 0, stream>>>(w, N_DIM * K_DIM, bits + 1);

  quant_kernel<<<M_DIM * K_DIM / (256 * 8), 256, 0, stream>>>(x, xq, bits + 0);
  quant_kernel<<<N_DIM * K_DIM / (256 * 8), 256, 0, stream>>>(w, wq, bits + 1);

  gemm_kernel<<<dim3(N_DIM / BN, M_DIM / BM), 256, 0, stream>>>(xq, wq, bias, bits, out);
}

// Round 2
// 667.400 us; speedup vs baseline: 1.0124x; 1.0124x over previous
//
#include <hip/hip_runtime.h>
#include <hip/hip_bf16.h>

// Problem shape (fixed by reference): x (2,4096,2048) f32, W (8192,2048) f32,
// bias (8192,) f32, out (2,4096,8192) f32.  GEMM: M=8192, N=8192, K=2048.
#define M_DIM 8192
#define N_DIM 8192
#define K_DIM 2048
#define BM 128
#define BN 128
#define BK 32

typedef __attribute__((ext_vector_type(8))) short bf16x8;   // 8 bf16 in 4 VGPRs
typedef __attribute__((ext_vector_type(4))) float floatx4;  // MFMA C/D

__device__ inline void gload_lds16(const void* g, void* l) {
  // global -> LDS direct DMA, 16 B per lane; LDS dest is wave-uniform base + lane*16
  __builtin_amdgcn_global_load_lds(
      (const __attribute__((address_space(1))) unsigned int*)g,
      (__attribute__((address_space(3))) unsigned int*)l, 16, 0, 0);
}

__device__ inline short f2bf(float f) {
  __hip_bfloat16 h = __float2bfloat16(f);  // RNE
  return *(short*)&h;
}

__device__ inline float round_bf16(float f) {
  __hip_bfloat16 h = __float2bfloat16(f);
  return __bfloat162float(h);
}

// ---------------- amax over BOTH tensors in one launch ----------------------
// blocks [0,1024): x -> bits[0]; blocks [1024,2048): w -> bits[1]
__global__ __launch_bounds__(256) void amax2_kernel(const float* __restrict__ x,
                                                    const float* __restrict__ w,
                                                    int n,
                                                    unsigned int* __restrict__ bits) {
  int b = blockIdx.x;
  const float* src;
  unsigned int* ob;
  if (b < 1024) { src = x; ob = bits + 0; } else { src = w; ob = bits + 1; b -= 1024; }
  int tid = threadIdx.x;
  int start = (b * 256 + tid) * 4;
  const int stride = 1024 * 256 * 4;
  float m = 0.0f;
  for (int i = start; i < n; i += stride) {
    float4 v = *(const float4*)(src + i);
    m = fmaxf(m, fmaxf(fmaxf(fabsf(v.x), fabsf(v.y)), fmaxf(fabsf(v.z), fabsf(v.w))));
  }
  for (int off = 32; off > 0; off >>= 1) m = fmaxf(m, __shfl_down(m, off));
  __shared__ float red[4];
  if ((tid & 63) == 0) red[tid >> 6] = m;
  __syncthreads();
  if (tid == 0) {
    m = fmaxf(fmaxf(red[0], red[1]), fmaxf(red[2], red[3]));
    atomicMax(ob, __float_as_uint(m));  // |x| >= 0: bit order == float order
  }
}

// ---------------- quantize BOTH tensors: dst = bf16(src / (amax/448)) -------
// blocks [0,8192): x -> xq; blocks [8192,16384): w -> wq
__global__ __launch_bounds__(256) void quant2_kernel(const float* __restrict__ x,
                                                     const float* __restrict__ w,
                                                     short* __restrict__ xq,
                                                     short* __restrict__ wq,
                                                     const unsigned int* __restrict__ bits) {
  int b = blockIdx.x;
  const float* src;
  short* dst;
  const unsigned int* ab;
  if (b < 8192) { src = x; dst = xq; ab = bits + 0; }
  else          { src = w; dst = wq; ab = bits + 1; b -= 8192; }
  float scale = __uint_as_float(*ab) / 448.0f;  // fp32 division, matches ref
  int idx = (b * 256 + threadIdx.x) * 8;
  float4 v0 = *(const float4*)(src + idx);
  float4 v1 = *(const float4*)(src + idx + 4);
  bf16x8 o;
  o[0] = f2bf(v0.x / scale);
  o[1] = f2bf(v0.y / scale);
  o[2] = f2bf(v0.z / scale);
  o[3] = f2bf(v0.w / scale);
  o[4] = f2bf(v1.x / scale);
  o[5] = f2bf(v1.y / scale);
  o[6] = f2bf(v1.z / scale);
  o[7] = f2bf(v1.w / scale);
  *(bf16x8*)(dst + idx) = o;
}

// ---------------- GEMM: C[m,n] = (sum_k A[m,k]*B[n,k]) rounded-bf16 * s + bias[n]
// m97 structure: 128x128 block, BK=32, 4 waves (2x2), each wave 4x4 tiles of
// 16x16x32 bf16 MFMA, staging via global_load_lds width=16, single LDS buffer.
//
// LDS bank-conflict swizzle (R2): tile rows are 64 B = 2 bank-groups, so the
// unswizzled fragment read is 8-way conflicted (3.35e7 conflict cycles in R1).
// Store logical 16B-chunk q of row r at physical chunk q ^ ((r>>1)&3).
// DMA dest must stay lane*16-contiguous, so the swizzle is applied to the
// *source* address each lane fetches; reads apply the same XOR. Result: the 64
// lanes of a b128 read cover all 8 bank-groups with 2 lanes/bank (free, m136).
__global__ __launch_bounds__(256, 2) void gemm_kernel(
    const short* __restrict__ A,   // Xq [M,K] bf16 bits
    const short* __restrict__ B,   // Wq [N,K] bf16 bits
    const float* __restrict__ bias,
    const unsigned int* __restrict__ amax_bits,  // [0]=x amax, [1]=w amax
    float* __restrict__ C) {
  __shared__ short As[BM * BK];  // [m][chunk-swizzled k]
  __shared__ short Bs[BN * BK];  // [n][chunk-swizzled k]

  const int tid = threadIdx.x;
  const int lane = tid & 63;
  const int waveId = tid >> 6;
  const int waveM = waveId >> 1;  // 0..1
  const int waveN = waveId & 1;   // 0..1
  const int m0 = blockIdx.y * BM;
  const int n0 = blockIdx.x * BN;

  // Staging: tile = 128 rows x 32 bf16 = 512 chunks of 16 B; 4 chunks per row.
  // Thread t fills LDS slots t and t+256 (dest = wave base + lane*16, fixed by
  // the DMA). Slot P = (row P>>2, phys chunk P&3) must hold logical chunk
  // (P&3) ^ ((row>>1)&3)  ->  source chunk q0 below. Rows r and r+64 share q0.
  const int r0 = tid >> 2;
  const int q0 = (tid & 3) ^ ((tid >> 3) & 3);  // swizzled source chunk
  const short* aSrc0 = A + (long)(m0 + r0) * K_DIM + q0 * 8;
  const short* aSrc1 = A + (long)(m0 + r0 + 64) * K_DIM + q0 * 8;
  const short* bSrc0 = B + (long)(n0 + r0) * K_DIM + q0 * 8;
  const short* bSrc1 = B + (long)(n0 + r0 + 64) * K_DIM + q0 * 8;
  short* aDst0 = As + tid * 8;
  short* aDst1 = As + (tid + 256) * 8;
  short* bDst0 = Bs + tid * 8;
  short* bDst1 = Bs + (tid + 256) * 8;

  floatx4 acc[4][4] = {};

  const int am = waveM * 64 + (lane & 15);  // A row base (add i*16)
  const int bn = waveN * 64 + (lane & 15);  // B row base (add j*16)
  // Fragment read: logical chunk c = lane>>4, row m = am + i*16.
  // Physical chunk = c ^ ((m>>1)&3); the XOR term = ((lane&15)>>1)&3 is
  // i-independent (am offsets are multiples of 16), so fold into ak.
  const int ak = ((lane >> 4) ^ ((lane >> 1) & 3)) * 8;

  for (int kt = 0; kt < K_DIM / BK; ++kt) {
    const int ko = kt * BK;
    gload_lds16(aSrc0 + ko, aDst0);
    gload_lds16(aSrc1 + ko, aDst1);
    gload_lds16(bSrc0 + ko, bDst0);
    gload_lds16(bSrc1 + ko, bDst1);
    __syncthreads();  // compiler drains vmcnt before barrier

    bf16x8 af[4], bfr[4];
#pragma unroll
    for (int i = 0; i < 4; ++i)
      af[i] = *(const bf16x8*)(As + (am + i * 16) * BK + ak);
#pragma unroll
    for (int j = 0; j < 4; ++j)
      bfr[j] = *(const bf16x8*)(Bs + (bn + j * 16) * BK + ak);

#pragma unroll
    for (int i = 0; i < 4; ++i)
#pragma unroll
      for (int j = 0; j < 4; ++j)
        acc[i][j] = __builtin_amdgcn_mfma_f32_16x16x32_bf16(af[i], bfr[j], acc[i][j], 0, 0, 0);

    __syncthreads();  // protect LDS before next stage
  }

  // Epilogue: ref = bf16(einsum).astype(f32) * (w_scale*x_scale) + bias
  const float sx = __uint_as_float(amax_bits[0]) / 448.0f;
  const float sw = __uint_as_float(amax_bits[1]) / 448.0f;
  const float s = sx * sw;
  const int col = lane & 15;
  const int rq = (lane >> 4) * 4;  // C/D: row = (lane>>4)*4 + reg, col = lane&15
#pragma unroll
  for (int j = 0; j < 4; ++j) {
    const int n = n0 + waveN * 64 + j * 16 + col;
    const float bv = bias[n];
#pragma unroll
    for (int i = 0; i < 4; ++i) {
      const int mBase = m0 + waveM * 64 + i * 16 + rq;
#pragma unroll
      for (int r = 0; r < 4; ++r) {
        float v = round_bf16(acc[i][j][r]);  // match XLA bf16 dot output demote
        C[(long)(mBase + r) * N_DIM + n] = v * s + bv;
      }
    }
  }
}

extern "C" void kernel_launch(void* const* d_in, const int* in_sizes, int n_in,
                              void* d_out, int out_size, void* d_ws, size_t ws_size,
                              hipStream_t stream) {
  const float* x = (const float*)d_in[0];     // (2,4096,2048)
  const float* w = (const float*)d_in[1];     // (8192,2048)
  const float* bias = (const float*)d_in[2];  // (8192,)
  float* out = (float*)d_out;

  // Workspace layout: [0..63] amax bits (u32[0]=x, u32[1]=w); then Xq; then Wq.
  unsigned int* bits = (unsigned int*)d_ws;
  short* xq = (short*)((char*)d_ws + 256);
  short* wq = (short*)((char*)d_ws + 256 + (size_t)M_DIM * K_DIM * sizeof(short));

  hipMemsetAsync(d_ws, 0, 64, stream);  // zero amax slots (ws is poisoned 0xAA)

  amax2_kernel<<<2048, 256, 0, stream>>>(x, w, M_DIM * K_DIM, bits);
  quant2_kernel<<<16384, 256, 0, stream>>>(x, w, xq, wq, bits);
  gemm_kernel<<<dim3(N_DIM / BN, M_DIM / BM), 256, 0, stream>>>(xq, wq, bias, bits, out);
}